// Round 20
// baseline (53.196 us; speedup 1.0000x reference)
//
#include <hip/hip_runtime.h>
#include <cstdint>

#define N_ATOMS 16384
#define NBLK 64
#define NTHR 256
#define G 24
#define NCELLS 13824
#define NCELLS_PAD 14336
#define CPT 14                    // cells per thread in k2 (1024 thr)
#define BOX_LO -48.0f
#define INV_CELL 0.25f            // cell side 4.0
#define SINIT 3.0e38f

// ws layout (~419 KB):
#define OFF_COUNTS 0              // int[2]: n_ctx, n_gen
#define OFF_ACELL 256             // u16[16384] per-atom cell (0xFFFF = gen)
#define OFF_START 33280           // int[14337] cell starts
#define OFF_GENIDX 90880          // int[16384]
#define OFF_CTX4 156672           // float4[16384] cell-sorted (x,y,z,|x|^2)

__device__ __forceinline__ int cell1(float x) {
    int c = (int)floorf((x - BOX_LO) * INV_CELL);
    return min(max(c, 0), G - 1);
}

__device__ __forceinline__ void ins3(float v, int vi,
                                     float& s1, float& s2, float& s3,
                                     int& i1, int& i2, int& i3)
{
    const bool b1 = v < s1, b2 = v < s2, b3 = v < s3;
    s3 = b2 ? s2 : (b3 ? v : s3);   i3 = b2 ? i2 : (b3 ? vi : i3);
    s2 = b1 ? s1 : (b2 ? v : s2);   i2 = b1 ? i1 : (b2 ? vi : i2);
    s1 = b1 ? v : s1;               i1 = b1 ? vi : i1;
}

// K1: classify + base_noise + per-atom cell id (no atomics)
__global__ __launch_bounds__(NTHR)
void k1_classify(const float* __restrict__ X,
                 const int* __restrict__ block_ids,
                 const unsigned int* __restrict__ mask,
                 const float* __restrict__ base_noise,
                 float* __restrict__ out,
                 unsigned short* __restrict__ acell)
{
    __shared__ int sflag;
    const int t = threadIdx.x;

    // mask dtype probe: int32 0/1 values vs packed bool bytes (R2-R19 validated)
    if (t == 0) sflag = 0;
    __syncthreads();
    if (mask[t] > 1u) sflag = 1;    // benign same-value race
    __syncthreads();
    const bool is_u8 = (sflag != 0);
    const unsigned char* m8 = (const unsigned char*)mask;

    const int i = blockIdx.x * NTHR + t;
    const int bid = block_ids[i];
    const bool g = is_u8 ? (m8[bid] != 0) : (mask[bid] != 0u);

    out[3 * i + 0] = base_noise[3 * i + 0];
    out[3 * i + 1] = base_noise[3 * i + 1];
    out[3 * i + 2] = base_noise[3 * i + 2];

    unsigned short c = 0xFFFFu;
    if (!g) {
        const float x = X[3 * i], y = X[3 * i + 1], z = X[3 * i + 2];
        c = (unsigned short)((cell1(z) * G + cell1(y)) * G + cell1(x));
    }
    acell[i] = c;
}

// K2': single-block LDS counting sort + fused scatter. Gen atoms use 64
// DISTRIBUTED bins (13824..13887, inside the pad) keyed by i>>8 — fixes
// R18's single-counter LDS-atomic serialization. genidx order is a free
// permutation (each k4 slot writes only out[ai]). cell_start[NCELLS]
// lands on the first gen bin start == n_ctx, as k4's row reads expect.
__global__ __launch_bounds__(1024)
void k2_sortscatter(const float* __restrict__ X,
                    const unsigned short* __restrict__ acell,
                    int* __restrict__ cell_start,
                    int* __restrict__ counts,
                    int* __restrict__ genidx,
                    float4* __restrict__ ctx4s)
{
    __shared__ int hist[NCELLS_PAD];          // 57,344 B
    __shared__ int wsum[16], wexc[16];
    const int t = threadIdx.x;
    const int wave = t >> 6, lane = t & 63;

    #pragma unroll
    for (int k = 0; k < CPT; ++k) hist[t * CPT + k] = 0;
    __syncthreads();

    // pass 1: histogram (ctx by cell; gen by 64 spread bins)
    #pragma unroll
    for (int it = 0; it < N_ATOMS / 1024; ++it) {
        const int i = it * 1024 + t;
        const unsigned short c = acell[i];
        const int bin = (c == 0xFFFFu) ? (NCELLS + ((i >> 8) & 63)) : (int)c;
        atomicAdd(&hist[bin], 1);
    }
    __syncthreads();

    // scan over all 14336 bins (pad incl. gen bins)
    int loc[CPT]; int sum = 0;
    #pragma unroll
    for (int k = 0; k < CPT; ++k) {
        const int v = hist[t * CPT + k];
        loc[k] = sum; sum += v;
    }
    int v = sum;
    #pragma unroll
    for (int d = 1; d < 64; d <<= 1) { const int u = __shfl_up(v, d); if (lane >= d) v += u; }
    if (lane == 63) wsum[wave] = v;
    __syncthreads();
    if (t < 16) {
        int v2 = wsum[t];
        const int orig = v2;
        #pragma unroll
        for (int d = 1; d < 16; d <<= 1) { const int u = __shfl_up(v2, d); if (t >= d) v2 += u; }
        wexc[t] = v2 - orig;
    }
    __syncthreads();
    const int base = wexc[wave] + (v - sum);
    #pragma unroll
    for (int k = 0; k < CPT; ++k) {
        const int st = base + loc[k];
        cell_start[t * CPT + k] = st;
        hist[t * CPT + k] = st;               // -> scatter cursor
    }
    if (t == 1023) cell_start[NCELLS_PAD] = base + sum;   // = N_ATOMS
    __syncthreads();

    const int nctx = hist[NCELLS];            // first gen bin start == n_ctx
    __syncthreads();                          // read before cursors mutate

    // pass 2: fused scatter
    #pragma unroll
    for (int it = 0; it < N_ATOMS / 1024; ++it) {
        const int i = it * 1024 + t;
        const unsigned short c = acell[i];
        const int bin = (c == 0xFFFFu) ? (NCELLS + ((i >> 8) & 63)) : (int)c;
        const int p = atomicAdd(&hist[bin], 1);
        if (c != 0xFFFFu) {
            const float x = X[3 * i], y = X[3 * i + 1], z = X[3 * i + 2];
            float xn = x * x; xn += y * y; xn += z * z;
            ctx4s[p] = make_float4(x, y, z, xn);
        } else {
            genidx[p - nctx] = i;
        }
    }
    if (t == 0) { counts[0] = nctx; counts[1] = N_ATOMS - nctx; }
}

// merge-network lane permutes: DPP (VALU) for 1,2,4,8; swizzle for 16; shfl 32
#define P_X1(v)  __builtin_amdgcn_update_dpp(v, v, 0xB1, 0xF, 0xF, false)
#define P_X2(v)  __builtin_amdgcn_update_dpp(v, v, 0x4E, 0xF, 0xF, false)
#define P_R4(v)  __builtin_amdgcn_update_dpp(v, v, 0x124, 0xF, 0xF, false)
#define P_R8(v)  __builtin_amdgcn_update_dpp(v, v, 0x128, 0xF, 0xF, false)
#define P_S16(v) __builtin_amdgcn_ds_swizzle(v, 0x401F)
#define P_X32(v) __shfl_xor(v, 32)

// K4: one wave per gen atom. Phase A: shuffle-free r<=1 box + ballot conv.
// Tail: ring (1,2] (1 segment-round, converges most), then x8-unrolled brute
// restart for the deep tail. Final merge: DPP/swizzle reduction network
// (7 DS ops/wave vs 36 bpermutes) — valid since all sq values are distinct.
__global__ __launch_bounds__(NTHR)
void k4_search(const float* __restrict__ X,
               const float* __restrict__ cnoise,
               const int* __restrict__ counts,
               const int* __restrict__ cell_start,
               const float4* __restrict__ ctx4s,
               const int* __restrict__ genidx,
               float* __restrict__ out)
{
    const int n_gen = counts[1];
    const int wave = threadIdx.x >> 6, lane = threadIdx.x & 63;
    if ((int)blockIdx.x * 4 >= n_gen) return;
    const int slot = (int)blockIdx.x * 4 + wave;
    if (slot >= n_gen) return;

    const int ai = genidx[slot];
    const float qx = X[3 * ai], qy = X[3 * ai + 1], qz = X[3 * ai + 2];
    float xnq = qx * qx; xnq += qy * qy; xnq += qz * qz;
    const int cqx = cell1(qx), cqy = cell1(qy), cqz = cell1(qz);

    float s1 = SINIT, s2 = SINIT, s3 = SINIT;
    int i1 = 0, i2 = 0, i3 = 0;

    // ---- phase A: r<=1 box as 9 row-segments, shuffle-free scan ----
    {
        int st = 0, cnt = 0;
        if (lane < 9) {
            const int dy = lane % 3 - 1, dz = lane / 3 - 1;
            const int cy = cqy + dy, cz = cqz + dz;
            if ((unsigned)cy < G && (unsigned)cz < G) {
                const int xlo = max(cqx - 1, 0), xhi = min(cqx + 1, G - 1);
                const int c0 = (cz * G + cy) * G + xlo;
                st = cell_start[c0];
                cnt = cell_start[c0 + (xhi - xlo + 1)] - st;
            }
        }
        int stv[9], base[10];
        base[0] = 0;
        #pragma unroll
        for (int k = 0; k < 9; ++k) {
            stv[k] = __builtin_amdgcn_readlane(st, k);     // VALU, uniform
            base[k + 1] = base[k] + __builtin_amdgcn_readlane(cnt, k);
        }
        const int T = base[9];
        const int nro = (T + 63) >> 6;
        if (nro > 0) {
            auto calcP = [&](int j) -> int {
                const int jc = min(j, T - 1);
                int p = stv[0] + jc;
                #pragma unroll
                for (int k = 1; k < 9; ++k)
                    p = (jc >= base[k]) ? stv[k] + (jc - base[k]) : p;
                return p;
            };
            int p0 = calcP(lane);
            float4 cc0 = ctx4s[p0];
            for (int ro = 0; ro < nro; ++ro) {
                int p1 = p0; float4 cc1 = cc0;
                if (ro + 1 < nro) { p1 = calcP((ro + 1) * 64 + lane); cc1 = ctx4s[p1]; }
                if (ro * 64 + lane < T) {
                    const float dot = qx * cc0.x + qy * cc0.y + qz * cc0.z;
                    const float sq = (xnq + cc0.w) - 2.0f * dot;
                    ins3(sq, p0, s1, s2, s3, i1, i2, i3);
                }
                p0 = p1; cc0 = cc1;
            }
        }
    }

    // ballot-count convergence: >=3 values below bound <=> merged m3 below
    auto converged = [&](float bnd) -> bool {
        const int c = __popcll(__ballot(s1 + 0.01f < bnd))
                    + __popcll(__ballot(s2 + 0.01f < bnd))
                    + __popcll(__ballot(s3 + 0.01f < bnd));
        return c >= 3;
    };

    bool done = converged(16.0f);            // (4*1)^2

    if (!done) {
        // ---- ring (1,2]: 34 segments, 1 round (R15-proven machinery) ----
        {
            const int P = 1, R = 2;
            const int B = 2 * R + 1;          // 5
            const int RP = R - P;             // 1
            const int PP = 2 * P + 1;         // 3
            const int A = 2 * RP * B;         // 10
            const int C = PP * 2 * RP;        // 6
            const int NS = A + C + 2 * PP * PP;  // 34
            int st = 0, cnt = 0;
            if (lane < NS) {
                const int u = lane;
                int dy, dz, xlo, xhi;
                if (u < A) {
                    const int q = u / B, rdy = u - q * B;
                    dz = (q < RP) ? (-R + q) : (P + 1 + (q - RP));
                    dy = rdy - R;
                    xlo = cqx - R; xhi = cqx + R;
                } else if (u < A + C) {
                    const int v2 = u - A, W = 2 * RP;
                    const int q = v2 / W, w = v2 - q * W;
                    dz = -P + q;
                    dy = (w < RP) ? (-R + w) : (P + 1 + (w - RP));
                    xlo = cqx - R; xhi = cqx + R;
                } else {
                    const int v2 = u - A - C;
                    const int side = v2 & 1, v3 = v2 >> 1;
                    dy = v3 % PP - P; dz = v3 / PP - P;
                    if (side) { xlo = cqx + P + 1; xhi = cqx + R; }
                    else      { xlo = cqx - R;     xhi = cqx - P - 1; }
                }
                const int cy = cqy + dy, cz = cqz + dz;
                if ((unsigned)cy < G && (unsigned)cz < G) {
                    xlo = max(xlo, 0); xhi = min(xhi, G - 1);
                    if (xlo <= xhi) {
                        const int c0 = (cz * G + cy) * G + xlo;
                        st = cell_start[c0];
                        cnt = cell_start[c0 + (xhi - xlo + 1)] - st;
                    }
                }
            }
            // prefix + flat scan (shuffle path; rare waves only)
            int pre = cnt;
            #pragma unroll
            for (int d = 1; d < 64; d <<= 1) {
                const int u = __shfl_up(pre, d);
                if (lane >= d) pre += u;
            }
            const int T = __shfl(pre, 63);
            const int ebase = pre - cnt;
            const int pk = st - ebase;
            const int iters = (T + 63) >> 6;
            for (int it = 0; it < iters; ++it) {
                const int j = it * 64 + lane;
                const int jc = min(j, T - 1);
                int L = 0;
                #pragma unroll
                for (int stp = 32; stp >= 1; stp >>= 1) {
                    const int cand = L + stp;
                    const int bv = __shfl(ebase, cand);
                    if (bv <= jc) L = cand;
                }
                const int p = __shfl(pk, L) + jc;
                const float4 cc = ctx4s[p];
                if (j < T) {
                    const float dot = qx * cc.x + qy * cc.y + qz * cc.z;
                    const float sq = (xnq + cc.w) - 2.0f * dot;
                    ins3(sq, p, s1, s2, s3, i1, i2, i3);
                }
            }
        }
        done = converged(64.0f);             // (4*2)^2

        if (!done) {
            // ---- deep tail: restart brute-force over ALL ctx, x8 unrolled ----
            s1 = SINIT; s2 = SINIT; s3 = SINIT;
            i1 = 0; i2 = 0; i3 = 0;
            const int n_ctx = counts[0];
            for (int base = 0; base < n_ctx; base += 512) {
                const int pa0 = min(base + 0 * 64 + lane, n_ctx - 1);
                const int pa1 = min(base + 1 * 64 + lane, n_ctx - 1);
                const int pa2 = min(base + 2 * 64 + lane, n_ctx - 1);
                const int pa3 = min(base + 3 * 64 + lane, n_ctx - 1);
                const int pa4 = min(base + 4 * 64 + lane, n_ctx - 1);
                const int pa5 = min(base + 5 * 64 + lane, n_ctx - 1);
                const int pa6 = min(base + 6 * 64 + lane, n_ctx - 1);
                const int pa7 = min(base + 7 * 64 + lane, n_ctx - 1);
                const float4 cv0 = ctx4s[pa0], cv1 = ctx4s[pa1];
                const float4 cv2 = ctx4s[pa2], cv3 = ctx4s[pa3];
                const float4 cv4 = ctx4s[pa4], cv5 = ctx4s[pa5];
                const float4 cv6 = ctx4s[pa6], cv7 = ctx4s[pa7];
                #define TAIL_INS(K, CV, PA) \
                    if (base + (K) * 64 + lane < n_ctx) { \
                        const float dot = qx * (CV).x + qy * (CV).y + qz * (CV).z; \
                        const float sq = (xnq + (CV).w) - 2.0f * dot; \
                        ins3(sq, (PA), s1, s2, s3, i1, i2, i3); \
                    }
                TAIL_INS(0, cv0, pa0) TAIL_INS(1, cv1, pa1)
                TAIL_INS(2, cv2, pa2) TAIL_INS(3, cv3, pa3)
                TAIL_INS(4, cv4, pa4) TAIL_INS(5, cv5, pa5)
                TAIL_INS(6, cv6, pa6) TAIL_INS(7, cv7, pa7)
                #undef TAIL_INS
            }
        }
    }

    // ---- final wave merge: DPP/swizzle reduction network (7 DS vs 36) ----
    #define MERGE_STEP(PERM) { \
        const float a = __int_as_float(PERM(__float_as_int(s1))); const int ja = PERM(i1); \
        const float b = __int_as_float(PERM(__float_as_int(s2))); const int jb = PERM(i2); \
        const float c = __int_as_float(PERM(__float_as_int(s3))); const int jc = PERM(i3); \
        ins3(a, ja, s1, s2, s3, i1, i2, i3); \
        ins3(b, jb, s1, s2, s3, i1, i2, i3); \
        ins3(c, jc, s1, s2, s3, i1, i2, i3); }
    MERGE_STEP(P_X1)    // xor1 (DPP quad_perm)
    MERGE_STEP(P_X2)    // xor2 (DPP quad_perm)
    MERGE_STEP(P_R4)    // ror4 (DPP row_ror — reduction coverage: quads q,q+1)
    MERGE_STEP(P_R8)    // ror8 (adds q+2,q+3 -> full row)
    MERGE_STEP(P_S16)   // xor16 (ds_swizzle)
    MERGE_STEP(P_X32)   // xor32 (bpermute)
    #undef MERGE_STEP

    if (lane == 0) {
        const float d1 = sqrtf(fmaxf(s1, 0.0f) + 1e-12f);
        const float d2 = sqrtf(fmaxf(s2, 0.0f) + 1e-12f);
        const float d3 = sqrtf(fmaxf(s3, 0.0f) + 1e-12f);
        float w1 = 1.0f / (d1 + 1e-8f);
        float w2 = 1.0f / (d2 + 1e-8f);
        float w3 = 1.0f / (d3 + 1e-8f);
        float wsum = w1 + w2;
        wsum += w3;
        w1 /= wsum; w2 /= wsum; w3 /= wsum;
        const float4 c1 = ctx4s[i1];
        const float4 c2 = ctx4s[i2];
        const float4 c3 = ctx4s[i3];
        float cxo = w1 * c1.x + w2 * c2.x; cxo += w3 * c3.x;
        float cyo = w1 * c1.y + w2 * c2.y; cyo += w3 * c3.y;
        float czo = w1 * c1.z + w2 * c2.z; czo += w3 * c3.z;
        out[3 * ai + 0] = cxo + 0.5f * cnoise[3 * ai + 0];
        out[3 * ai + 1] = cyo + 0.5f * cnoise[3 * ai + 1];
        out[3 * ai + 2] = czo + 0.5f * cnoise[3 * ai + 2];
    }
}

extern "C" void kernel_launch(void* const* d_in, const int* in_sizes, int n_in,
                              void* d_out, int out_size, void* d_ws, size_t ws_size,
                              hipStream_t stream) {
    const float* X          = (const float*)d_in[0];
    const float* base_noise = (const float*)d_in[1];
    const float* cnoise     = (const float*)d_in[2];
    const int*   block_ids  = (const int*)d_in[3];
    const unsigned int* gmask = (const unsigned int*)d_in[4];
    float* out = (float*)d_out;

    char* ws = (char*)d_ws;
    int*    counts     = (int*)(ws + OFF_COUNTS);
    unsigned short* acell = (unsigned short*)(ws + OFF_ACELL);
    int*    cell_start = (int*)(ws + OFF_START);
    int*    genidx     = (int*)(ws + OFF_GENIDX);
    float4* ctx4s      = (float4*)(ws + OFF_CTX4);

    k1_classify<<<NBLK, NTHR, 0, stream>>>(X, block_ids, gmask, base_noise,
                                           out, acell);
    k2_sortscatter<<<1, 1024, 0, stream>>>(X, acell, cell_start, counts,
                                           genidx, ctx4s);
    k4_search<<<N_ATOMS / 4, NTHR, 0, stream>>>(X, cnoise, counts, cell_start,
                                                ctx4s, genidx, out);
}

// Round 21
// 47.670 us; speedup vs baseline: 1.1159x; 1.1159x over previous
//
#include <hip/hip_runtime.h>
#include <cstdint>

#define N_ATOMS 16384
#define NBLK 64
#define NTHR 256
#define G 24
#define NCELLS 13824
#define NCELLS_PAD 14336
#define CPT 14                    // cells per thread in k2 (1024 thr)
#define BOX_LO -48.0f
#define INV_CELL 0.25f            // cell side 4.0
#define SINIT 3.0e38f

// ws layout (~476 KB):
#define OFF_COUNTS 0              // int[2]: n_ctx, n_gen
#define OFF_BLKGEN 256            // int[64]
#define OFF_BLKGOFF 512           // int[64]
#define OFF_FLAGS 1024            // u64[256] gen bit per atom
#define OFF_ACELL 3072            // u16[16384] per-atom cell (0xFFFF = gen)
#define OFF_POS 35840             // int[16384] ctx scatter position
#define OFF_START 101376          // int[14337] cell starts
#define OFF_GENIDX 158976         // int[16384]
#define OFF_CTX4 224512           // float4[16384] cell-sorted (x,y,z,|x|^2)

__device__ __forceinline__ int cell1(float x) {
    int c = (int)floorf((x - BOX_LO) * INV_CELL);
    return min(max(c, 0), G - 1);
}

__device__ __forceinline__ void ins3(float v, int vi,
                                     float& s1, float& s2, float& s3,
                                     int& i1, int& i2, int& i3)
{
    const bool b1 = v < s1, b2 = v < s2, b3 = v < s3;
    s3 = b2 ? s2 : (b3 ? v : s3);   i3 = b2 ? i2 : (b3 ? vi : i3);
    s2 = b1 ? s1 : (b2 ? v : s2);   i2 = b1 ? i1 : (b2 ? vi : i2);
    s1 = b1 ? v : s1;               i1 = b1 ? vi : i1;
}

// K1: classify + base_noise + gen flags + per-atom cell id (R15 proven)
__global__ __launch_bounds__(NTHR)
void k1_classify(const float* __restrict__ X,
                 const int* __restrict__ block_ids,
                 const unsigned int* __restrict__ mask,
                 const float* __restrict__ base_noise,
                 float* __restrict__ out,
                 unsigned long long* __restrict__ flags,
                 int* __restrict__ blk_gen,
                 unsigned short* __restrict__ acell)
{
    __shared__ int sflag;
    __shared__ int wg[4];
    const int t = threadIdx.x;
    const int wave = t >> 6, lane = t & 63;

    // mask dtype probe: int32 0/1 values vs packed bool bytes (R2-R20 validated)
    if (t == 0) sflag = 0;
    __syncthreads();
    if (mask[t] > 1u) sflag = 1;    // benign same-value race
    __syncthreads();
    const bool is_u8 = (sflag != 0);
    const unsigned char* m8 = (const unsigned char*)mask;

    const int i = blockIdx.x * NTHR + t;
    const int bid = block_ids[i];
    const bool g = is_u8 ? (m8[bid] != 0) : (mask[bid] != 0u);

    out[3 * i + 0] = base_noise[3 * i + 0];
    out[3 * i + 1] = base_noise[3 * i + 1];
    out[3 * i + 2] = base_noise[3 * i + 2];

    const unsigned long long mg = __ballot(g);
    if (lane == 0) { flags[blockIdx.x * 4 + wave] = mg; wg[wave] = __popcll(mg); }
    __syncthreads();
    if (t == 0) blk_gen[blockIdx.x] = wg[0] + wg[1] + wg[2] + wg[3];

    unsigned short c = 0xFFFFu;
    if (!g) {
        const float x = X[3 * i], y = X[3 * i + 1], z = X[3 * i + 2];
        c = (unsigned short)((cell1(z) * G + cell1(y)) * G + cell1(x));
    }
    acell[i] = c;
}

// K2: single-block LDS counting sort: histogram -> scan -> positions (R15)
__global__ __launch_bounds__(1024)
void k2_sort(const unsigned short* __restrict__ acell,
             int* __restrict__ cell_start,
             int* __restrict__ pos,
             const int* __restrict__ blk_gen,
             int* __restrict__ blk_goff,
             int* __restrict__ counts)
{
    __shared__ int hist[NCELLS_PAD];          // 57,344 B
    __shared__ int wsum[16], wexc[16];
    const int t = threadIdx.x;
    const int wave = t >> 6, lane = t & 63;

    #pragma unroll
    for (int k = 0; k < CPT; ++k) hist[t * CPT + k] = 0;
    __syncthreads();

    #pragma unroll
    for (int it = 0; it < N_ATOMS / 1024; ++it) {
        const unsigned short c = acell[it * 1024 + t];
        if (c != 0xFFFFu) atomicAdd(&hist[c], 1);
    }
    __syncthreads();

    int loc[CPT]; int sum = 0;
    #pragma unroll
    for (int k = 0; k < CPT; ++k) {
        const int v = hist[t * CPT + k];
        loc[k] = sum; sum += v;
    }
    int v = sum;
    #pragma unroll
    for (int d = 1; d < 64; d <<= 1) { const int u = __shfl_up(v, d); if (lane >= d) v += u; }
    if (lane == 63) wsum[wave] = v;
    __syncthreads();
    if (t < 16) {
        int v2 = wsum[t];
        const int orig = v2;
        #pragma unroll
        for (int d = 1; d < 16; d <<= 1) { const int u = __shfl_up(v2, d); if (t >= d) v2 += u; }
        wexc[t] = v2 - orig;
    }
    __syncthreads();
    const int base = wexc[wave] + (v - sum);
    #pragma unroll
    for (int k = 0; k < CPT; ++k) {
        const int st = base + loc[k];
        cell_start[t * CPT + k] = st;
        hist[t * CPT + k] = st;               // -> cursor
    }
    if (t == 1023) cell_start[NCELLS_PAD] = base + sum;
    __syncthreads();

    #pragma unroll
    for (int it = 0; it < N_ATOMS / 1024; ++it) {
        const int i = it * 1024 + t;
        const unsigned short c = acell[i];
        if (c != 0xFFFFu) pos[i] = atomicAdd(&hist[c], 1);
    }

    if (t < 64) {
        const int o = blk_gen[t];
        int s = o;
        #pragma unroll
        for (int d = 1; d < 64; d <<= 1) { const int u = __shfl_up(s, d); if (t >= d) s += u; }
        blk_goff[t] = s - o;
        if (t == 63) { counts[1] = s; counts[0] = N_ATOMS - s; }
    }
}

// K3: 64-block parallel scatter (no atomics) — R15 proven (single-block
// fused scatter serializes the 8192 random stores on one CU: +7-8us).
__global__ __launch_bounds__(NTHR)
void k3_scatter(const float* __restrict__ X,
                const unsigned long long* __restrict__ flags,
                const int* __restrict__ blk_goff,
                const int* __restrict__ pos,
                float4* __restrict__ ctx4s,
                int* __restrict__ genidx)
{
    const int t = threadIdx.x;
    const int wave = t >> 6, lane = t & 63;
    const int i = blockIdx.x * NTHR + t;
    const unsigned long long fw = flags[blockIdx.x * 4 + wave];
    const bool g = (fw >> lane) & 1ull;
    if (g) {
        int og = blk_goff[blockIdx.x];
        #pragma unroll
        for (int w = 0; w < 4; ++w) {
            if (w < wave) og += __popcll(flags[blockIdx.x * 4 + w]);
        }
        const unsigned long long below = (1ull << lane) - 1ull;
        og += __popcll(fw & below);
        genidx[og] = i;
    } else {
        const float x = X[3 * i], y = X[3 * i + 1], z = X[3 * i + 2];
        float xn = x * x; xn += y * y; xn += z * z;
        ctx4s[pos[i]] = make_float4(x, y, z, xn);
    }
}

// merge-network lane permutes: DPP (VALU) for 1,2,4,8; swizzle for 16; shfl 32
// (refcheck'd in R20: absmax 0.03125)
#define P_X1(v)  __builtin_amdgcn_update_dpp(v, v, 0xB1, 0xF, 0xF, false)
#define P_X2(v)  __builtin_amdgcn_update_dpp(v, v, 0x4E, 0xF, 0xF, false)
#define P_R4(v)  __builtin_amdgcn_update_dpp(v, v, 0x124, 0xF, 0xF, false)
#define P_R8(v)  __builtin_amdgcn_update_dpp(v, v, 0x128, 0xF, 0xF, false)
#define P_S16(v) __builtin_amdgcn_ds_swizzle(v, 0x401F)
#define P_X32(v) __shfl_xor(v, 32)

// K4: one wave per gen atom. Phase A: shuffle-free r<=1 box + ballot conv.
// Tail: ring (1,2] (1 round, catches mid-tail), then x4-unrolled brute
// restart for deep tail (x4 caps VGPR to protect bulk occupancy — R19's
// x8 likely cost occupancy). Final merge: DPP network (7 DS ops vs 36).
__global__ __launch_bounds__(NTHR)
void k4_search(const float* __restrict__ X,
               const float* __restrict__ cnoise,
               const int* __restrict__ counts,
               const int* __restrict__ cell_start,
               const float4* __restrict__ ctx4s,
               const int* __restrict__ genidx,
               float* __restrict__ out)
{
    const int n_gen = counts[1];
    const int wave = threadIdx.x >> 6, lane = threadIdx.x & 63;
    if ((int)blockIdx.x * 4 >= n_gen) return;
    const int slot = (int)blockIdx.x * 4 + wave;
    if (slot >= n_gen) return;

    const int ai = genidx[slot];
    const float qx = X[3 * ai], qy = X[3 * ai + 1], qz = X[3 * ai + 2];
    float xnq = qx * qx; xnq += qy * qy; xnq += qz * qz;
    const int cqx = cell1(qx), cqy = cell1(qy), cqz = cell1(qz);

    float s1 = SINIT, s2 = SINIT, s3 = SINIT;
    int i1 = 0, i2 = 0, i3 = 0;

    // ---- phase A: r<=1 box as 9 row-segments, shuffle-free scan ----
    {
        int st = 0, cnt = 0;
        if (lane < 9) {
            const int dy = lane % 3 - 1, dz = lane / 3 - 1;
            const int cy = cqy + dy, cz = cqz + dz;
            if ((unsigned)cy < G && (unsigned)cz < G) {
                const int xlo = max(cqx - 1, 0), xhi = min(cqx + 1, G - 1);
                const int c0 = (cz * G + cy) * G + xlo;
                st = cell_start[c0];
                cnt = cell_start[c0 + (xhi - xlo + 1)] - st;
            }
        }
        int stv[9], base[10];
        base[0] = 0;
        #pragma unroll
        for (int k = 0; k < 9; ++k) {
            stv[k] = __builtin_amdgcn_readlane(st, k);     // VALU, uniform
            base[k + 1] = base[k] + __builtin_amdgcn_readlane(cnt, k);
        }
        const int T = base[9];
        const int nro = (T + 63) >> 6;
        if (nro > 0) {
            auto calcP = [&](int j) -> int {
                const int jc = min(j, T - 1);
                int p = stv[0] + jc;
                #pragma unroll
                for (int k = 1; k < 9; ++k)
                    p = (jc >= base[k]) ? stv[k] + (jc - base[k]) : p;
                return p;
            };
            int p0 = calcP(lane);
            float4 cc0 = ctx4s[p0];
            for (int ro = 0; ro < nro; ++ro) {
                int p1 = p0; float4 cc1 = cc0;
                if (ro + 1 < nro) { p1 = calcP((ro + 1) * 64 + lane); cc1 = ctx4s[p1]; }
                if (ro * 64 + lane < T) {
                    const float dot = qx * cc0.x + qy * cc0.y + qz * cc0.z;
                    const float sq = (xnq + cc0.w) - 2.0f * dot;
                    ins3(sq, p0, s1, s2, s3, i1, i2, i3);
                }
                p0 = p1; cc0 = cc1;
            }
        }
    }

    // ballot-count convergence: >=3 values below bound <=> merged m3 below
    auto converged = [&](float bnd) -> bool {
        const int c = __popcll(__ballot(s1 + 0.01f < bnd))
                    + __popcll(__ballot(s2 + 0.01f < bnd))
                    + __popcll(__ballot(s3 + 0.01f < bnd));
        return c >= 3;
    };

    bool done = converged(16.0f);            // (4*1)^2

    if (!done) {
        // ---- ring (1,2]: 34 segments, 1 round (R20 refcheck'd) ----
        {
            const int P = 1, R = 2;
            const int B = 2 * R + 1;          // 5
            const int RP = R - P;             // 1
            const int PP = 2 * P + 1;         // 3
            const int A = 2 * RP * B;         // 10
            const int C = PP * 2 * RP;        // 6
            const int NS = A + C + 2 * PP * PP;  // 34
            int st = 0, cnt = 0;
            if (lane < NS) {
                const int u = lane;
                int dy, dz, xlo, xhi;
                if (u < A) {
                    const int q = u / B, rdy = u - q * B;
                    dz = (q < RP) ? (-R + q) : (P + 1 + (q - RP));
                    dy = rdy - R;
                    xlo = cqx - R; xhi = cqx + R;
                } else if (u < A + C) {
                    const int v2 = u - A, W = 2 * RP;
                    const int q = v2 / W, w = v2 - q * W;
                    dz = -P + q;
                    dy = (w < RP) ? (-R + w) : (P + 1 + (w - RP));
                    xlo = cqx - R; xhi = cqx + R;
                } else {
                    const int v2 = u - A - C;
                    const int side = v2 & 1, v3 = v2 >> 1;
                    dy = v3 % PP - P; dz = v3 / PP - P;
                    if (side) { xlo = cqx + P + 1; xhi = cqx + R; }
                    else      { xlo = cqx - R;     xhi = cqx - P - 1; }
                }
                const int cy = cqy + dy, cz = cqz + dz;
                if ((unsigned)cy < G && (unsigned)cz < G) {
                    xlo = max(xlo, 0); xhi = min(xhi, G - 1);
                    if (xlo <= xhi) {
                        const int c0 = (cz * G + cy) * G + xlo;
                        st = cell_start[c0];
                        cnt = cell_start[c0 + (xhi - xlo + 1)] - st;
                    }
                }
            }
            int pre = cnt;
            #pragma unroll
            for (int d = 1; d < 64; d <<= 1) {
                const int u = __shfl_up(pre, d);
                if (lane >= d) pre += u;
            }
            const int T = __shfl(pre, 63);
            const int ebase = pre - cnt;
            const int pk = st - ebase;
            const int iters = (T + 63) >> 6;
            for (int it = 0; it < iters; ++it) {
                const int j = it * 64 + lane;
                const int jc = min(j, T - 1);
                int L = 0;
                #pragma unroll
                for (int stp = 32; stp >= 1; stp >>= 1) {
                    const int cand = L + stp;
                    const int bv = __shfl(ebase, cand);
                    if (bv <= jc) L = cand;
                }
                const int p = __shfl(pk, L) + jc;
                const float4 cc = ctx4s[p];
                if (j < T) {
                    const float dot = qx * cc.x + qy * cc.y + qz * cc.z;
                    const float sq = (xnq + cc.w) - 2.0f * dot;
                    ins3(sq, p, s1, s2, s3, i1, i2, i3);
                }
            }
        }
        done = converged(64.0f);             // (4*2)^2

        if (!done) {
            // ---- deep tail: restart brute-force over ALL ctx, x4 unrolled ----
            s1 = SINIT; s2 = SINIT; s3 = SINIT;
            i1 = 0; i2 = 0; i3 = 0;
            const int n_ctx = counts[0];
            for (int base = 0; base < n_ctx; base += 256) {
                const int pa0 = min(base + 0 * 64 + lane, n_ctx - 1);
                const int pa1 = min(base + 1 * 64 + lane, n_ctx - 1);
                const int pa2 = min(base + 2 * 64 + lane, n_ctx - 1);
                const int pa3 = min(base + 3 * 64 + lane, n_ctx - 1);
                const float4 cv0 = ctx4s[pa0], cv1 = ctx4s[pa1];
                const float4 cv2 = ctx4s[pa2], cv3 = ctx4s[pa3];
                #define TAIL_INS(K, CV, PA) \
                    if (base + (K) * 64 + lane < n_ctx) { \
                        const float dot = qx * (CV).x + qy * (CV).y + qz * (CV).z; \
                        const float sq = (xnq + (CV).w) - 2.0f * dot; \
                        ins3(sq, (PA), s1, s2, s3, i1, i2, i3); \
                    }
                TAIL_INS(0, cv0, pa0) TAIL_INS(1, cv1, pa1)
                TAIL_INS(2, cv2, pa2) TAIL_INS(3, cv3, pa3)
                #undef TAIL_INS
            }
        }
    }

    // ---- final wave merge: DPP/swizzle reduction network (R20 refcheck'd) ----
    #define MERGE_STEP(PERM) { \
        const float a = __int_as_float(PERM(__float_as_int(s1))); const int ja = PERM(i1); \
        const float b = __int_as_float(PERM(__float_as_int(s2))); const int jb = PERM(i2); \
        const float c = __int_as_float(PERM(__float_as_int(s3))); const int jc = PERM(i3); \
        ins3(a, ja, s1, s2, s3, i1, i2, i3); \
        ins3(b, jb, s1, s2, s3, i1, i2, i3); \
        ins3(c, jc, s1, s2, s3, i1, i2, i3); }
    MERGE_STEP(P_X1)
    MERGE_STEP(P_X2)
    MERGE_STEP(P_R4)
    MERGE_STEP(P_R8)
    MERGE_STEP(P_S16)
    MERGE_STEP(P_X32)
    #undef MERGE_STEP

    if (lane == 0) {
        const float d1 = sqrtf(fmaxf(s1, 0.0f) + 1e-12f);
        const float d2 = sqrtf(fmaxf(s2, 0.0f) + 1e-12f);
        const float d3 = sqrtf(fmaxf(s3, 0.0f) + 1e-12f);
        float w1 = 1.0f / (d1 + 1e-8f);
        float w2 = 1.0f / (d2 + 1e-8f);
        float w3 = 1.0f / (d3 + 1e-8f);
        float wsum = w1 + w2;
        wsum += w3;
        w1 /= wsum; w2 /= wsum; w3 /= wsum;
        const float4 c1 = ctx4s[i1];
        const float4 c2 = ctx4s[i2];
        const float4 c3 = ctx4s[i3];
        float cxo = w1 * c1.x + w2 * c2.x; cxo += w3 * c3.x;
        float cyo = w1 * c1.y + w2 * c2.y; cyo += w3 * c3.y;
        float czo = w1 * c1.z + w2 * c2.z; czo += w3 * c3.z;
        out[3 * ai + 0] = cxo + 0.5f * cnoise[3 * ai + 0];
        out[3 * ai + 1] = cyo + 0.5f * cnoise[3 * ai + 1];
        out[3 * ai + 2] = czo + 0.5f * cnoise[3 * ai + 2];
    }
}

extern "C" void kernel_launch(void* const* d_in, const int* in_sizes, int n_in,
                              void* d_out, int out_size, void* d_ws, size_t ws_size,
                              hipStream_t stream) {
    const float* X          = (const float*)d_in[0];
    const float* base_noise = (const float*)d_in[1];
    const float* cnoise     = (const float*)d_in[2];
    const int*   block_ids  = (const int*)d_in[3];
    const unsigned int* gmask = (const unsigned int*)d_in[4];
    float* out = (float*)d_out;

    char* ws = (char*)d_ws;
    int*    counts     = (int*)(ws + OFF_COUNTS);
    int*    blk_gen    = (int*)(ws + OFF_BLKGEN);
    int*    blk_goff   = (int*)(ws + OFF_BLKGOFF);
    unsigned long long* flags = (unsigned long long*)(ws + OFF_FLAGS);
    unsigned short* acell = (unsigned short*)(ws + OFF_ACELL);
    int*    pos        = (int*)(ws + OFF_POS);
    int*    cell_start = (int*)(ws + OFF_START);
    int*    genidx     = (int*)(ws + OFF_GENIDX);
    float4* ctx4s      = (float4*)(ws + OFF_CTX4);

    k1_classify<<<NBLK, NTHR, 0, stream>>>(X, block_ids, gmask, base_noise,
                                           out, flags, blk_gen, acell);
    k2_sort<<<1, 1024, 0, stream>>>(acell, cell_start, pos, blk_gen, blk_goff, counts);
    k3_scatter<<<NBLK, NTHR, 0, stream>>>(X, flags, blk_goff, pos, ctx4s, genidx);
    k4_search<<<N_ATOMS / 4, NTHR, 0, stream>>>(X, cnoise, counts, cell_start,
                                                ctx4s, genidx, out);
}

// Round 22
// 47.625 us; speedup vs baseline: 1.1170x; 1.0009x over previous
//
#include <hip/hip_runtime.h>
#include <cstdint>

#define N_ATOMS 16384
#define NBLK 64
#define NTHR 256
#define G 24
#define NCELLS 13824
#define NCELLS_PAD 14336
#define CPT 14                    // cells per thread in k2 (1024 thr)
#define BOX_LO -48.0f
#define INV_CELL 0.25f            // cell side 4.0
#define SINIT 3.0e38f

// ws layout (~484 KB):
#define OFF_COUNTS 0              // int[2]: n_ctx, n_gen
#define OFF_ACELL 256             // u16[16384]: cell | 0x8000 if gen
#define OFF_POS 33280             // int[16384]: scatter position (both classes)
#define OFF_START 98816           // int[14337]: ctx cell starts
#define OFF_GENIDX 156416         // int[16384]: gen atoms CELL-SORTED
#define OFF_CTX4 222208           // float4[16384] cell-sorted (x,y,z,|x|^2)

__device__ __forceinline__ int cell1(float x) {
    int c = (int)floorf((x - BOX_LO) * INV_CELL);
    return min(max(c, 0), G - 1);
}

__device__ __forceinline__ void ins3(float v, int vi,
                                     float& s1, float& s2, float& s3,
                                     int& i1, int& i2, int& i3)
{
    const bool b1 = v < s1, b2 = v < s2, b3 = v < s3;
    s3 = b2 ? s2 : (b3 ? v : s3);   i3 = b2 ? i2 : (b3 ? vi : i3);
    s2 = b1 ? s1 : (b2 ? v : s2);   i2 = b1 ? i1 : (b2 ? vi : i2);
    s1 = b1 ? v : s1;               i1 = b1 ? vi : i1;
}

// K1: classify + base_noise + per-atom cell id for ALL atoms (gen tagged 0x8000)
__global__ __launch_bounds__(NTHR)
void k1_classify(const float* __restrict__ X,
                 const int* __restrict__ block_ids,
                 const unsigned int* __restrict__ mask,
                 const float* __restrict__ base_noise,
                 float* __restrict__ out,
                 unsigned short* __restrict__ acell)
{
    __shared__ int sflag;
    const int t = threadIdx.x;

    // mask dtype probe: int32 0/1 values vs packed bool bytes (R2-R21 validated)
    if (t == 0) sflag = 0;
    __syncthreads();
    if (mask[t] > 1u) sflag = 1;    // benign same-value race
    __syncthreads();
    const bool is_u8 = (sflag != 0);
    const unsigned char* m8 = (const unsigned char*)mask;

    const int i = blockIdx.x * NTHR + t;
    const int bid = block_ids[i];
    const bool g = is_u8 ? (m8[bid] != 0) : (mask[bid] != 0u);

    out[3 * i + 0] = base_noise[3 * i + 0];
    out[3 * i + 1] = base_noise[3 * i + 1];
    out[3 * i + 2] = base_noise[3 * i + 2];

    const float x = X[3 * i], y = X[3 * i + 1], z = X[3 * i + 2];
    const unsigned short c =
        (unsigned short)(((cell1(z) * G + cell1(y)) * G + cell1(x)) |
                         (g ? 0x8000 : 0));
    acell[i] = c;
}

// K2: single-block LDS counting sort with PACKED ctx/gen histogram
// (lo16 = ctx count, hi16 = gen count; prefix-sum carries never cross:
// lo sums <= 16384, hi sums <= 16384<<16 < 2^31). Produces ctx cell_start,
// per-atom scatter pos for BOTH classes -> gen atoms become CELL-SORTED
// (free permutation: each k4 slot writes only out[ai]) for k4 L1 locality.
__global__ __launch_bounds__(1024)
void k2_sort(const unsigned short* __restrict__ acell,
             int* __restrict__ cell_start,
             int* __restrict__ pos,
             int* __restrict__ counts)
{
    __shared__ int hist[NCELLS_PAD];          // 57,344 B
    __shared__ int wsum[16], wexc[16];
    const int t = threadIdx.x;
    const int wave = t >> 6, lane = t & 63;

    #pragma unroll
    for (int k = 0; k < CPT; ++k) hist[t * CPT + k] = 0;
    __syncthreads();

    // pass 1: packed histogram
    #pragma unroll
    for (int it = 0; it < N_ATOMS / 1024; ++it) {
        const unsigned short c = acell[it * 1024 + t];
        const int bin = c & 0x3FFF;
        const int inc = (c & 0x8000) ? 65536 : 1;
        atomicAdd(&hist[bin], inc);
    }
    __syncthreads();

    // packed scan: 14 cells/thread -> wave prefix -> cross-wave prefix
    int loc[CPT]; int sum = 0;
    #pragma unroll
    for (int k = 0; k < CPT; ++k) {
        const int v = hist[t * CPT + k];
        loc[k] = sum; sum += v;
    }
    int v = sum;
    #pragma unroll
    for (int d = 1; d < 64; d <<= 1) { const int u = __shfl_up(v, d); if (lane >= d) v += u; }
    if (lane == 63) wsum[wave] = v;
    __syncthreads();
    if (t < 16) {
        int v2 = wsum[t];
        const int orig = v2;
        #pragma unroll
        for (int d = 1; d < 16; d <<= 1) { const int u = __shfl_up(v2, d); if (t >= d) v2 += u; }
        wexc[t] = v2 - orig;
    }
    __syncthreads();
    const int base = wexc[wave] + (v - sum);
    #pragma unroll
    for (int k = 0; k < CPT; ++k) {
        const int st = base + loc[k];          // packed (ctx_start, gen_start)
        cell_start[t * CPT + k] = st & 0xFFFF; // ctx starts for k4
        hist[t * CPT + k] = st;                // packed cursor
    }
    if (t == 1023) {
        const int tot = base + sum;
        cell_start[NCELLS_PAD] = tot & 0xFFFF; // = n_ctx
        counts[0] = tot & 0xFFFF;
        counts[1] = tot >> 16;
    }
    __syncthreads();

    // pass 2: per-atom scatter positions (ctx: lo cursor; gen: hi cursor)
    #pragma unroll
    for (int it = 0; it < N_ATOMS / 1024; ++it) {
        const int i = it * 1024 + t;
        const unsigned short c = acell[i];
        const int bin = c & 0x3FFF;
        const int inc = (c & 0x8000) ? 65536 : 1;
        const int old = atomicAdd(&hist[bin], inc);
        pos[i] = (c & 0x8000) ? (old >> 16) : (old & 0xFFFF);
    }
}

// K3: 64-block parallel scatter (no atomics); gen slots are cell-sorted
__global__ __launch_bounds__(NTHR)
void k3_scatter(const float* __restrict__ X,
                const unsigned short* __restrict__ acell,
                const int* __restrict__ pos,
                float4* __restrict__ ctx4s,
                int* __restrict__ genidx)
{
    const int t = threadIdx.x;
    const int i = blockIdx.x * NTHR + t;
    const unsigned short c = acell[i];
    if (c & 0x8000) {
        genidx[pos[i]] = i;
    } else {
        const float x = X[3 * i], y = X[3 * i + 1], z = X[3 * i + 2];
        float xn = x * x; xn += y * y; xn += z * z;
        ctx4s[pos[i]] = make_float4(x, y, z, xn);
    }
}

// merge-network lane permutes: DPP (VALU) for 1,2,4,8; swizzle 16; shfl 32
// (refcheck'd R20/R21)
#define P_X1(v)  __builtin_amdgcn_update_dpp(v, v, 0xB1, 0xF, 0xF, false)
#define P_X2(v)  __builtin_amdgcn_update_dpp(v, v, 0x4E, 0xF, 0xF, false)
#define P_R4(v)  __builtin_amdgcn_update_dpp(v, v, 0x124, 0xF, 0xF, false)
#define P_R8(v)  __builtin_amdgcn_update_dpp(v, v, 0x128, 0xF, 0xF, false)
#define P_S16(v) __builtin_amdgcn_ds_swizzle(v, 0x401F)
#define P_X32(v) __shfl_xor(v, 32)

// K4: R21 verbatim (one wave/atom; shuffle-free phase A; ballot convergence;
// ring (1,2]; x4 brute restart deep tail; DPP merge network). Gen atoms now
// arrive CELL-SORTED -> block-level L1 reuse of candidate lines.
__global__ __launch_bounds__(NTHR)
void k4_search(const float* __restrict__ X,
               const float* __restrict__ cnoise,
               const int* __restrict__ counts,
               const int* __restrict__ cell_start,
               const float4* __restrict__ ctx4s,
               const int* __restrict__ genidx,
               float* __restrict__ out)
{
    const int n_gen = counts[1];
    const int wave = threadIdx.x >> 6, lane = threadIdx.x & 63;
    if ((int)blockIdx.x * 4 >= n_gen) return;
    const int slot = (int)blockIdx.x * 4 + wave;
    if (slot >= n_gen) return;

    const int ai = genidx[slot];
    const float qx = X[3 * ai], qy = X[3 * ai + 1], qz = X[3 * ai + 2];
    float xnq = qx * qx; xnq += qy * qy; xnq += qz * qz;
    const int cqx = cell1(qx), cqy = cell1(qy), cqz = cell1(qz);

    float s1 = SINIT, s2 = SINIT, s3 = SINIT;
    int i1 = 0, i2 = 0, i3 = 0;

    // ---- phase A: r<=1 box as 9 row-segments, shuffle-free scan ----
    {
        int st = 0, cnt = 0;
        if (lane < 9) {
            const int dy = lane % 3 - 1, dz = lane / 3 - 1;
            const int cy = cqy + dy, cz = cqz + dz;
            if ((unsigned)cy < G && (unsigned)cz < G) {
                const int xlo = max(cqx - 1, 0), xhi = min(cqx + 1, G - 1);
                const int c0 = (cz * G + cy) * G + xlo;
                st = cell_start[c0];
                cnt = cell_start[c0 + (xhi - xlo + 1)] - st;
            }
        }
        int stv[9], base[10];
        base[0] = 0;
        #pragma unroll
        for (int k = 0; k < 9; ++k) {
            stv[k] = __builtin_amdgcn_readlane(st, k);     // VALU, uniform
            base[k + 1] = base[k] + __builtin_amdgcn_readlane(cnt, k);
        }
        const int T = base[9];
        const int nro = (T + 63) >> 6;
        if (nro > 0) {
            auto calcP = [&](int j) -> int {
                const int jc = min(j, T - 1);
                int p = stv[0] + jc;
                #pragma unroll
                for (int k = 1; k < 9; ++k)
                    p = (jc >= base[k]) ? stv[k] + (jc - base[k]) : p;
                return p;
            };
            int p0 = calcP(lane);
            float4 cc0 = ctx4s[p0];
            for (int ro = 0; ro < nro; ++ro) {
                int p1 = p0; float4 cc1 = cc0;
                if (ro + 1 < nro) { p1 = calcP((ro + 1) * 64 + lane); cc1 = ctx4s[p1]; }
                if (ro * 64 + lane < T) {
                    const float dot = qx * cc0.x + qy * cc0.y + qz * cc0.z;
                    const float sq = (xnq + cc0.w) - 2.0f * dot;
                    ins3(sq, p0, s1, s2, s3, i1, i2, i3);
                }
                p0 = p1; cc0 = cc1;
            }
        }
    }

    // ballot-count convergence: >=3 values below bound <=> merged m3 below
    auto converged = [&](float bnd) -> bool {
        const int c = __popcll(__ballot(s1 + 0.01f < bnd))
                    + __popcll(__ballot(s2 + 0.01f < bnd))
                    + __popcll(__ballot(s3 + 0.01f < bnd));
        return c >= 3;
    };

    bool done = converged(16.0f);            // (4*1)^2

    if (!done) {
        // ---- ring (1,2]: 34 segments, 1 round ----
        {
            const int P = 1, R = 2;
            const int B = 2 * R + 1;          // 5
            const int RP = R - P;             // 1
            const int PP = 2 * P + 1;         // 3
            const int A = 2 * RP * B;         // 10
            const int C = PP * 2 * RP;        // 6
            const int NS = A + C + 2 * PP * PP;  // 34
            int st = 0, cnt = 0;
            if (lane < NS) {
                const int u = lane;
                int dy, dz, xlo, xhi;
                if (u < A) {
                    const int q = u / B, rdy = u - q * B;
                    dz = (q < RP) ? (-R + q) : (P + 1 + (q - RP));
                    dy = rdy - R;
                    xlo = cqx - R; xhi = cqx + R;
                } else if (u < A + C) {
                    const int v2 = u - A, W = 2 * RP;
                    const int q = v2 / W, w = v2 - q * W;
                    dz = -P + q;
                    dy = (w < RP) ? (-R + w) : (P + 1 + (w - RP));
                    xlo = cqx - R; xhi = cqx + R;
                } else {
                    const int v2 = u - A - C;
                    const int side = v2 & 1, v3 = v2 >> 1;
                    dy = v3 % PP - P; dz = v3 / PP - P;
                    if (side) { xlo = cqx + P + 1; xhi = cqx + R; }
                    else      { xlo = cqx - R;     xhi = cqx - P - 1; }
                }
                const int cy = cqy + dy, cz = cqz + dz;
                if ((unsigned)cy < G && (unsigned)cz < G) {
                    xlo = max(xlo, 0); xhi = min(xhi, G - 1);
                    if (xlo <= xhi) {
                        const int c0 = (cz * G + cy) * G + xlo;
                        st = cell_start[c0];
                        cnt = cell_start[c0 + (xhi - xlo + 1)] - st;
                    }
                }
            }
            int pre = cnt;
            #pragma unroll
            for (int d = 1; d < 64; d <<= 1) {
                const int u = __shfl_up(pre, d);
                if (lane >= d) pre += u;
            }
            const int T = __shfl(pre, 63);
            const int ebase = pre - cnt;
            const int pk = st - ebase;
            const int iters = (T + 63) >> 6;
            for (int it = 0; it < iters; ++it) {
                const int j = it * 64 + lane;
                const int jc = min(j, T - 1);
                int L = 0;
                #pragma unroll
                for (int stp = 32; stp >= 1; stp >>= 1) {
                    const int cand = L + stp;
                    const int bv = __shfl(ebase, cand);
                    if (bv <= jc) L = cand;
                }
                const int p = __shfl(pk, L) + jc;
                const float4 cc = ctx4s[p];
                if (j < T) {
                    const float dot = qx * cc.x + qy * cc.y + qz * cc.z;
                    const float sq = (xnq + cc.w) - 2.0f * dot;
                    ins3(sq, p, s1, s2, s3, i1, i2, i3);
                }
            }
        }
        done = converged(64.0f);             // (4*2)^2

        if (!done) {
            // ---- deep tail: restart brute-force over ALL ctx, x4 unrolled ----
            s1 = SINIT; s2 = SINIT; s3 = SINIT;
            i1 = 0; i2 = 0; i3 = 0;
            const int n_ctx = counts[0];
            for (int base = 0; base < n_ctx; base += 256) {
                const int pa0 = min(base + 0 * 64 + lane, n_ctx - 1);
                const int pa1 = min(base + 1 * 64 + lane, n_ctx - 1);
                const int pa2 = min(base + 2 * 64 + lane, n_ctx - 1);
                const int pa3 = min(base + 3 * 64 + lane, n_ctx - 1);
                const float4 cv0 = ctx4s[pa0], cv1 = ctx4s[pa1];
                const float4 cv2 = ctx4s[pa2], cv3 = ctx4s[pa3];
                #define TAIL_INS(K, CV, PA) \
                    if (base + (K) * 64 + lane < n_ctx) { \
                        const float dot = qx * (CV).x + qy * (CV).y + qz * (CV).z; \
                        const float sq = (xnq + (CV).w) - 2.0f * dot; \
                        ins3(sq, (PA), s1, s2, s3, i1, i2, i3); \
                    }
                TAIL_INS(0, cv0, pa0) TAIL_INS(1, cv1, pa1)
                TAIL_INS(2, cv2, pa2) TAIL_INS(3, cv3, pa3)
                #undef TAIL_INS
            }
        }
    }

    // ---- final wave merge: DPP/swizzle reduction network ----
    #define MERGE_STEP(PERM) { \
        const float a = __int_as_float(PERM(__float_as_int(s1))); const int ja = PERM(i1); \
        const float b = __int_as_float(PERM(__float_as_int(s2))); const int jb = PERM(i2); \
        const float c = __int_as_float(PERM(__float_as_int(s3))); const int jc = PERM(i3); \
        ins3(a, ja, s1, s2, s3, i1, i2, i3); \
        ins3(b, jb, s1, s2, s3, i1, i2, i3); \
        ins3(c, jc, s1, s2, s3, i1, i2, i3); }
    MERGE_STEP(P_X1)
    MERGE_STEP(P_X2)
    MERGE_STEP(P_R4)
    MERGE_STEP(P_R8)
    MERGE_STEP(P_S16)
    MERGE_STEP(P_X32)
    #undef MERGE_STEP

    if (lane == 0) {
        const float d1 = sqrtf(fmaxf(s1, 0.0f) + 1e-12f);
        const float d2 = sqrtf(fmaxf(s2, 0.0f) + 1e-12f);
        const float d3 = sqrtf(fmaxf(s3, 0.0f) + 1e-12f);
        float w1 = 1.0f / (d1 + 1e-8f);
        float w2 = 1.0f / (d2 + 1e-8f);
        float w3 = 1.0f / (d3 + 1e-8f);
        float wsum = w1 + w2;
        wsum += w3;
        w1 /= wsum; w2 /= wsum; w3 /= wsum;
        const float4 c1 = ctx4s[i1];
        const float4 c2 = ctx4s[i2];
        const float4 c3 = ctx4s[i3];
        float cxo = w1 * c1.x + w2 * c2.x; cxo += w3 * c3.x;
        float cyo = w1 * c1.y + w2 * c2.y; cyo += w3 * c3.y;
        float czo = w1 * c1.z + w2 * c2.z; czo += w3 * c3.z;
        out[3 * ai + 0] = cxo + 0.5f * cnoise[3 * ai + 0];
        out[3 * ai + 1] = cyo + 0.5f * cnoise[3 * ai + 1];
        out[3 * ai + 2] = czo + 0.5f * cnoise[3 * ai + 2];
    }
}

extern "C" void kernel_launch(void* const* d_in, const int* in_sizes, int n_in,
                              void* d_out, int out_size, void* d_ws, size_t ws_size,
                              hipStream_t stream) {
    const float* X          = (const float*)d_in[0];
    const float* base_noise = (const float*)d_in[1];
    const float* cnoise     = (const float*)d_in[2];
    const int*   block_ids  = (const int*)d_in[3];
    const unsigned int* gmask = (const unsigned int*)d_in[4];
    float* out = (float*)d_out;

    char* ws = (char*)d_ws;
    int*    counts     = (int*)(ws + OFF_COUNTS);
    unsigned short* acell = (unsigned short*)(ws + OFF_ACELL);
    int*    pos        = (int*)(ws + OFF_POS);
    int*    cell_start = (int*)(ws + OFF_START);
    int*    genidx     = (int*)(ws + OFF_GENIDX);
    float4* ctx4s      = (float4*)(ws + OFF_CTX4);

    k1_classify<<<NBLK, NTHR, 0, stream>>>(X, block_ids, gmask, base_noise,
                                           out, acell);
    k2_sort<<<1, 1024, 0, stream>>>(acell, cell_start, pos, counts);
    k3_scatter<<<NBLK, NTHR, 0, stream>>>(X, acell, pos, ctx4s, genidx);
    k4_search<<<N_ATOMS / 4, NTHR, 0, stream>>>(X, cnoise, counts, cell_start,
                                                ctx4s, genidx, out);
}